// Round 1
// baseline (7097.408 us; speedup 1.0000x reference)
//
#include <hip/hip_runtime.h>
#include <math.h>

#define B_    16
#define QL_   32
#define DL_   12
#define RSZ_  500
#define T_    2
#define DW_   256
#define DH_   512
#define HP_   256
#define NW_   50000
#define NE_   100000
#define NSEQD (T_*B_*RSZ_)   // 16000

__device__ __forceinline__ float sigf(float x){ return 1.0f/(1.0f+expf(-x)); }

// ---------------------------------------------------------------------------
// Combined GRU weight: Wc[dir][k][n], k in [0,512) = [x(256) | h(256)],
// n in [0,1024) = [r(256) | z(256) | xn(256) | ghn(256)].
// r,z rows: Wx and Wh summed into one K=512 row. xn: Wx only. ghn: Wh only.
// ---------------------------------------------------------------------------
__global__ void k_build_comb(const float* __restrict__ Wx, const float* __restrict__ Wh,
                             float* __restrict__ Wc) {
  int idx = blockIdx.x*256 + threadIdx.x;   // 2*512*1024 total
  int dir = idx >> 19;
  int k   = (idx >> 10) & 511;
  int n   = idx & 1023;
  float v = 0.f;
  if (n < 512) {
    v = (k < 256) ? Wx[(dir*768 + n)*256 + k] : Wh[(dir*768 + n)*256 + (k-256)];
  } else if (n < 768) {
    if (k < 256) v = Wx[(dir*768 + n)*256 + k];
  } else {
    if (k >= 256) v = Wh[(dir*768 + (n-256))*256 + (k-256)];
  }
  Wc[idx] = v;
}

__device__ __forceinline__ float gate_bias(int n, const float* bxd, const float* bhd) {
  return (n < 512) ? (bxd[n] + bhd[n]) : ((n < 768) ? bxd[n] : bhd[n-256]);
}

// ---------------------------------------------------------------------------
// Question GRU step. grid (1, 16 j-chunks, 2 dirs), block 256.
// A = [emb[tok] | h] (16x512) in LDS; block computes n = {j,256+j,512+j,768+j}
// for j in [j0,j0+16) -> self-contained gate epilogue. Ping-pong h buffers
// (j-split blocks may not update h in place).
// ---------------------------------------------------------------------------
__global__ __launch_bounds__(256) void k_qstep(
    const int* __restrict__ tokens, const float* __restrict__ emb,
    const float* __restrict__ Wc, const float* __restrict__ bx, const float* __restrict__ bh,
    const float* __restrict__ h_in, float* __restrict__ h_out, float* __restrict__ hs,
    int step)
{
  int dir = blockIdx.z;
  int l = dir ? (QL_-1-step) : step;
  int tid = threadIdx.x;
  __shared__ float4 A4[16*128];
  __shared__ float  gl[16*64];
  const float* hi = h_in + dir*(16*256);

  for (int f = tid; f < 2048; f += 256) {
    int m = f >> 7, c4 = f & 127;
    float4 v;
    if (c4 < 64) {
      int tk = tokens[m*QL_ + l];
      v = ((const float4*)emb)[(size_t)tk*64 + c4];
    } else {
      v = ((const float4*)hi)[m*64 + (c4-64)];
    }
    A4[m*128 + c4] = v;
  }
  __syncthreads();

  int nl = tid & 63, mg = tid >> 6;
  int piece = nl >> 4, jj = nl & 15;
  int j0 = blockIdx.y*16;
  int n = piece*256 + j0 + jj;
  const float* bxd = bx + dir*768;
  const float* bhd = bh + dir*768;
  float bias = gate_bias(n, bxd, bhd);
  float acc0=bias, acc1=bias, acc2=bias, acc3=bias;
  const float* W = Wc + dir*(512*1024);
  for (int k = 0; k < 512; k += 4) {
    float w0 = W[(k+0)*1024 + n];
    float w1 = W[(k+1)*1024 + n];
    float w2 = W[(k+2)*1024 + n];
    float w3 = W[(k+3)*1024 + n];
    int kc = k >> 2;
    float4 a0 = A4[(mg*4+0)*128 + kc];
    float4 a1 = A4[(mg*4+1)*128 + kc];
    float4 a2 = A4[(mg*4+2)*128 + kc];
    float4 a3 = A4[(mg*4+3)*128 + kc];
    acc0 += a0.x*w0 + a0.y*w1 + a0.z*w2 + a0.w*w3;
    acc1 += a1.x*w0 + a1.y*w1 + a1.z*w2 + a1.w*w3;
    acc2 += a2.x*w0 + a2.y*w1 + a2.z*w2 + a2.w*w3;
    acc3 += a3.x*w0 + a3.y*w1 + a3.z*w2 + a3.w*w3;
  }
  gl[(mg*4+0)*64 + nl] = acc0;
  gl[(mg*4+1)*64 + nl] = acc1;
  gl[(mg*4+2)*64 + nl] = acc2;
  gl[(mg*4+3)*64 + nl] = acc3;
  __syncthreads();

  int m = tid >> 4, j2 = tid & 15;
  int j = j0 + j2;
  float r  = sigf(gl[m*64 + j2]);
  float z  = sigf(gl[m*64 + 16 + j2]);
  float xn = gl[m*64 + 32 + j2];
  float gn = gl[m*64 + 48 + j2];
  float nt = tanhf(xn + r*gn);
  float hold = hi[m*256 + j];
  float hn = (1.f - z)*nt + z*hold;
  int tk = tokens[m*QL_ + l];
  float hnew = (tk != 0) ? hn : hold;
  h_out[dir*(16*256) + m*256 + j] = hnew;
  hs[((dir*16 + m)*QL_ + l)*256 + j] = hnew;
}

// ---------------------------------------------------------------------------
// Desc GRU step. grid (1000, 1, 2 dirs), block 256. Block owns 16 sequences,
// full N=1024 -> in-place h update is safe. LDS: A (32KB) unioned with gates
// transpose buffer (64KB total). Thread tile: 16 m x 4 n (acc[16][4]);
// B reads perfectly coalesced (1KB/wave), A reads are LDS broadcasts.
// ---------------------------------------------------------------------------
__global__ __launch_bounds__(256) void k_dstep(
    const int* __restrict__ tokens, const float* __restrict__ emb,
    const float* __restrict__ Wc, const float* __restrict__ bx, const float* __restrict__ bh,
    float* __restrict__ h, int step)
{
  int dir = blockIdx.z;
  int l = dir ? (DL_-1-step) : step;
  int seq0 = blockIdx.x * 16;
  int tid = threadIdx.x;
  __shared__ float4 smem[4096];          // 64 KB
  float* gl = (float*)smem;              // gates view (16x1024), reuses A space
  float* hd = h + (size_t)dir*NSEQD*256;

  for (int f = tid; f < 2048; f += 256) {
    int m = f >> 7, c4 = f & 127;
    int s = seq0 + m;
    float4 v;
    if (c4 < 64) {
      int tk = tokens[s*DL_ + l];
      v = ((const float4*)emb)[(size_t)tk*64 + c4];
    } else {
      v = ((const float4*)hd)[(size_t)s*64 + (c4-64)];
    }
    smem[m*128 + c4] = v;
  }
  __syncthreads();

  int nb = tid * 4;                      // 4 consecutive n per thread
  const float* bxd = bx + dir*768;
  const float* bhd = bh + dir*768;
  float acc[16][4];
  #pragma unroll
  for (int ni = 0; ni < 4; ++ni) {
    float bias = gate_bias(nb + ni, bxd, bhd);
    #pragma unroll
    for (int mi = 0; mi < 16; ++mi) acc[mi][ni] = bias;
  }

  const float4* W4 = (const float4*)(Wc + (size_t)dir*(512*1024));
  for (int k = 0; k < 512; k += 4) {
    float bs[4][4];
    #pragma unroll
    for (int kk = 0; kk < 4; ++kk) {
      float4 u0 = W4[(size_t)(k+kk)*256 + tid];
      bs[kk][0]=u0.x; bs[kk][1]=u0.y; bs[kk][2]=u0.z; bs[kk][3]=u0.w;
    }
    int kc = k >> 2;
    #pragma unroll
    for (int mi = 0; mi < 16; ++mi) {
      float4 a = smem[mi*128 + kc];
      #pragma unroll
      for (int ni = 0; ni < 4; ++ni)
        acc[mi][ni] += a.x*bs[0][ni] + a.y*bs[1][ni] + a.z*bs[2][ni] + a.w*bs[3][ni];
    }
  }
  __syncthreads();                       // all A reads done before gl overwrite
  #pragma unroll
  for (int mi = 0; mi < 16; ++mi)
    #pragma unroll
    for (int ni = 0; ni < 4; ++ni)
      gl[mi*1024 + nb + ni] = acc[mi][ni];
  __syncthreads();

  int j = tid;
  #pragma unroll
  for (int m = 0; m < 16; ++m) {
    float r  = sigf(gl[m*1024 + j]);
    float z  = sigf(gl[m*1024 + 256 + j]);
    float xn = gl[m*1024 + 512 + j];
    float gn = gl[m*1024 + 768 + j];
    float nt = tanhf(xn + r*gn);
    int s = seq0 + m;
    float hold = hd[(size_t)s*256 + j];
    float hn = (1.f - z)*nt + z*hold;
    int tk = tokens[s*DL_ + l];
    hd[(size_t)s*256 + j] = (tk != 0) ? hn : hold;
  }
}

// q_emb = concat(hT_f, hT_b)
__global__ void k_qemb(const float* __restrict__ h0, float* __restrict__ qemb){
  int o = blockIdx.x*256 + threadIdx.x;  // 8192
  int b = o >> 9, c = o & 511;
  qemb[o] = (c < 256) ? h0[b*256 + c] : h0[16*256 + b*256 + (c-256)];
}

// q_word_h = concat(hs_f, hs_b) * mask
__global__ void k_qwh(const float* __restrict__ hs, const int* __restrict__ tokens,
                      float* __restrict__ qwh){
  int o = blockIdx.x*256 + threadIdx.x;  // 262144
  int b = o >> 14;
  int rem = o & 16383;
  int l = rem >> 9, c = rem & 511;
  int cc = c & 255, dirn = c >> 8;
  float v = hs[((dirn*16 + b)*QL_ + l)*256 + cc];
  float msk = (tokens[b*QL_ + l] != 0) ? 1.f : 0.f;
  qwh[o] = v * msk;
}

// Per t: cq = tanh(q_emb @ step_W^T + b); att softmax; ctx; u = ctx*rel_W.
// grid 16 (one block per batch row).
__global__ __launch_bounds__(256) void k_attn(
    const float* __restrict__ qemb, const float* __restrict__ qwh,
    const float* __restrict__ sW, const float* __restrict__ sb,
    const float* __restrict__ relW, float* __restrict__ u, int t)
{
  int b = blockIdx.x, tid = threadIdx.x;
  __shared__ float qe[512];
  __shared__ float cq[512];
  __shared__ float lg[32];
  __shared__ float dist[32];
  qe[tid]     = qemb[b*512 + tid];
  qe[tid+256] = qemb[b*512 + 256 + tid];
  __syncthreads();
  const float4* qe4 = (const float4*)qe;
  for (int nn = 0; nn < 2; ++nn) {
    int n = tid + nn*256;
    const float4* w4 = (const float4*)(sW + ((size_t)t*512 + n)*512);
    float acc = 0.f;
    for (int k4 = 0; k4 < 128; ++k4) {
      float4 w = w4[k4]; float4 q = qe4[k4];
      acc += w.x*q.x + w.y*q.y + w.z*q.z + w.w*q.w;
    }
    cq[n] = tanhf(acc + sb[t*512 + n]);
  }
  __syncthreads();
  if (tid < 32) {
    const float4* r4 = (const float4*)(qwh + ((size_t)b*QL_ + tid)*512);
    const float4* c4 = (const float4*)cq;
    float acc = 0.f;
    for (int k4 = 0; k4 < 128; ++k4) {
      float4 w = r4[k4]; float4 q = c4[k4];
      acc += w.x*q.x + w.y*q.y + w.z*q.z + w.w*q.w;
    }
    lg[tid] = acc;
  }
  __syncthreads();
  if (tid == 0) {
    float mx = lg[0];
    for (int i = 1; i < 32; ++i) mx = fmaxf(mx, lg[i]);
    float s = 0.f;
    for (int i = 0; i < 32; ++i) { float e = expf(lg[i]-mx); dist[i] = e; s += e; }
    float inv = 1.f/s;
    for (int i = 0; i < 32; ++i) dist[i] *= inv;
  }
  __syncthreads();
  for (int nn = 0; nn < 2; ++nn) {
    int c = tid + nn*256;
    float acc = 0.f;
    #pragma unroll 4
    for (int ll = 0; ll < 32; ++ll)
      acc += dist[ll] * qwh[((size_t)b*QL_ + ll)*512 + c];
    u[b*512 + c] = acc * relW[c];
  }
}

// d_prob[b][r] = sigmoid( sum_c u[b][c] * d_emb[s][c] + rel_b ). One wave/output.
__global__ __launch_bounds__(256) void k_dlogit(
    const float* __restrict__ u, const float* __restrict__ dh,
    const float* __restrict__ relb, float* __restrict__ dprob, int t)
{
  int w = threadIdx.x >> 6, lane = threadIdx.x & 63;
  int o = blockIdx.x*4 + w;               // 0..7999 = b*500+r
  int b = o / 500;
  int s = t*(B_*RSZ_) + o;
  const float* e0 = dh + (size_t)s*256;
  const float* e1 = dh + (size_t)NSEQD*256 + (size_t)s*256;
  float acc = 0.f;
  #pragma unroll
  for (int i = 0; i < 4; ++i) {
    int c = lane + i*64;
    acc += u[b*512 + c]       * e0[c];
    acc += u[b*512 + 256 + c] * e1[c];
  }
  #pragma unroll
  for (int off = 32; off; off >>= 1) acc += __shfl_down(acc, off);
  if (lane == 0) dprob[o] = sigf(acc + relb[0]);
}

// obj_p = gather(e_src, sub) [clamped to 1 for t>0] * d_prob; scatter-add at obj.
__global__ void k_scatter(const int* __restrict__ pair, const float* __restrict__ dprob,
                          const float* __restrict__ esrc, float* __restrict__ edst,
                          int t, int clampflag)
{
  int o = blockIdx.x*256 + threadIdx.x;
  if (o >= B_*RSZ_) return;
  int b = o / RSZ_, r = o % RSZ_;
  const int* pp = pair + (((size_t)t*B_ + b)*RSZ_ + r)*2;
  int sub = pp[0], obj = pp[1];
  float v = esrc[(size_t)b*NE_ + sub];
  if (clampflag) v = fminf(v, 1.0f);
  atomicAdd(edst + (size_t)b*NE_ + obj, v * dprob[o]);
}

// out[b][e] = min(e_fin[b][e],1) * sigmoid(q_emb[b]·qcls_W[e] + qcls_b[e]).
// Wave: 4 b-groups x 16 k-slices; shfl_xor reduce over the 16-lane k dimension.
__global__ __launch_bounds__(256) void k_final(
    const float* __restrict__ qemb, const float* __restrict__ W,
    const float* __restrict__ bias, const float* __restrict__ efin,
    float* __restrict__ out)
{
  int tid = threadIdx.x;
  int lane = tid & 63;
  int ks = lane & 15, bg = lane >> 4;
  int b = (tid >> 6)*4 + bg;
  float q[32];
  {
    const float4* q4 = (const float4*)(qemb + b*512 + ks*32);
    #pragma unroll
    for (int i = 0; i < 8; ++i) {
      float4 v = q4[i];
      q[4*i]=v.x; q[4*i+1]=v.y; q[4*i+2]=v.z; q[4*i+3]=v.w;
    }
  }
  int e0 = blockIdx.x*256;
  int eend = (e0+256 < NE_) ? e0+256 : NE_;
  for (int e = e0; e < eend; ++e) {
    const float4* w4 = (const float4*)(W + (size_t)e*512 + ks*32);
    float acc = 0.f;
    #pragma unroll
    for (int i = 0; i < 8; ++i) {
      float4 v = w4[i];
      acc += v.x*q[4*i] + v.y*q[4*i+1] + v.z*q[4*i+2] + v.w*q[4*i+3];
    }
    acc += __shfl_xor(acc, 1);
    acc += __shfl_xor(acc, 2);
    acc += __shfl_xor(acc, 4);
    acc += __shfl_xor(acc, 8);
    if (ks == 0) {
      float msk = sigf(acc + bias[e]);
      float ev = fminf(efin[(size_t)b*NE_ + e], 1.0f);
      out[(size_t)b*NE_ + e] = ev * msk;
    }
  }
}

extern "C" void kernel_launch(void* const* d_in, const int* in_sizes, int n_in,
                              void* d_out, int out_size, void* d_ws, size_t ws_size,
                              hipStream_t stream)
{
  const int*   questions = (const int*)d_in[0];
  const float* e_s   = (const float*)d_in[1];
  const int*   pair  = (const int*)d_in[2];
  const int*   desc  = (const int*)d_in[3];
  const float* emb   = (const float*)d_in[4];
  const float* qWx   = (const float*)d_in[5];
  const float* qWh   = (const float*)d_in[6];
  const float* qbx   = (const float*)d_in[7];
  const float* qbh   = (const float*)d_in[8];
  const float* dWx   = (const float*)d_in[9];
  const float* dWh   = (const float*)d_in[10];
  const float* dbx   = (const float*)d_in[11];
  const float* dbh   = (const float*)d_in[12];
  const float* stepW = (const float*)d_in[13];
  const float* stepb = (const float*)d_in[14];
  const float* relW  = (const float*)d_in[15];
  const float* relb  = (const float*)d_in[16];
  const float* qclsW = (const float*)d_in[17];
  const float* qclsb = (const float*)d_in[18];
  float* out = (float*)d_out;

  char* ws = (char*)d_ws;
  size_t off = 0;
  auto alloc = [&](size_t bytes)->void* {
    void* p = ws + off; off += (bytes + 255) & ~(size_t)255; return p;
  };
  float* WcQ  = (float*)alloc((size_t)2*512*1024*sizeof(float));   // 4 MB
  float* WcD  = (float*)alloc((size_t)2*512*1024*sizeof(float));   // 4 MB
  float* qh   = (float*)alloc((size_t)2*2*16*256*sizeof(float));   // ping-pong [buf][dir][16][256]
  float* qhs  = (float*)alloc((size_t)2*16*QL_*256*sizeof(float)); // 1 MB
  float* qemb = (float*)alloc((size_t)16*512*sizeof(float));
  float* qwh  = (float*)alloc((size_t)16*QL_*512*sizeof(float));   // 1 MB
  float* dh   = (float*)alloc((size_t)2*NSEQD*256*sizeof(float));  // 32.8 MB
  float* u    = (float*)alloc((size_t)16*512*sizeof(float));
  float* dprob= (float*)alloc((size_t)B_*RSZ_*sizeof(float));
  float* ebuf = (float*)alloc((size_t)2*B_*NE_*sizeof(float));     // 12.8 MB

  hipMemsetAsync(qh,   0, (size_t)2*2*16*256*sizeof(float), stream);
  hipMemsetAsync(dh,   0, (size_t)2*NSEQD*256*sizeof(float), stream);
  hipMemsetAsync(ebuf, 0, (size_t)2*B_*NE_*sizeof(float), stream);

  k_build_comb<<<4096, 256, 0, stream>>>(qWx, qWh, WcQ);
  k_build_comb<<<4096, 256, 0, stream>>>(dWx, dWh, WcD);

  for (int s = 0; s < QL_; ++s) {
    const float* hin = qh + (size_t)(s & 1)*(2*16*256);
    float*      hout = qh + (size_t)((s+1) & 1)*(2*16*256);
    k_qstep<<<dim3(1,16,2), 256, 0, stream>>>(questions, emb, WcQ, qbx, qbh, hin, hout, qhs, s);
  }
  k_qemb<<<32, 256, 0, stream>>>(qh, qemb);     // final h in buf 0 (32 steps even)
  k_qwh<<<1024, 256, 0, stream>>>(qhs, questions, qwh);

  for (int s = 0; s < DL_; ++s)
    k_dstep<<<dim3(NSEQD/16,1,2), 256, 0, stream>>>(desc, emb, WcD, dbx, dbh, dh, s);

  for (int t = 0; t < T_; ++t) {
    k_attn<<<16, 256, 0, stream>>>(qemb, qwh, stepW, stepb, relW, u, t);
    k_dlogit<<<2000, 256, 0, stream>>>(u, dh, relb, dprob, t);
    const float* esrc = (t == 0) ? e_s : ebuf;
    float* edst = ebuf + (size_t)t*B_*NE_;
    k_scatter<<<32, 256, 0, stream>>>(pair, dprob, esrc, edst, t, t);
  }
  k_final<<<(NE_+255)/256, 256, 0, stream>>>(qemb, qclsW, qclsb, ebuf + (size_t)B_*NE_, out);
}

// Round 2
// 2684.831 us; speedup vs baseline: 2.6435x; 2.6435x over previous
//
#include <hip/hip_runtime.h>
#include <math.h>

#define B_    16
#define QL_   32
#define DL_   12
#define RSZ_  500
#define T_    2
#define DW_   256
#define DH_   512
#define HP_   256
#define NW_   50000
#define NE_   100000
#define NSEQD (T_*B_*RSZ_)   // 16000

typedef _Float16 half8 __attribute__((ext_vector_type(8)));
typedef float   floatx4 __attribute__((ext_vector_type(4)));

__device__ __forceinline__ float sigf(float x){ return 1.0f/(1.0f+expf(-x)); }

// ---------------------------------------------------------------------------
// Q-GRU combined fp32 weight (unchanged from round 1).
// ---------------------------------------------------------------------------
__global__ void k_build_comb(const float* __restrict__ Wx, const float* __restrict__ Wh,
                             float* __restrict__ Wc) {
  int idx = blockIdx.x*256 + threadIdx.x;
  int dir = idx >> 19;
  int k   = (idx >> 10) & 511;
  int n   = idx & 1023;
  float v = 0.f;
  if (n < 512) {
    v = (k < 256) ? Wx[(dir*768 + n)*256 + k] : Wh[(dir*768 + n)*256 + (k-256)];
  } else if (n < 768) {
    if (k < 256) v = Wx[(dir*768 + n)*256 + k];
  } else {
    if (k >= 256) v = Wh[(dir*768 + (n-256))*256 + (k-256)];
  }
  Wc[idx] = v;
}

__device__ __forceinline__ float gate_bias(int n, const float* bxd, const float* bhd) {
  return (n < 512) ? (bxd[n] + bhd[n]) : ((n < 768) ? bxd[n] : bhd[n-256]);
}

// ---------------------------------------------------------------------------
// Desc-GRU fp16 B^T weights. Per dir (393216 elems):
//   [0, 262144):        Brz [n=512][k=512]  n<256: r_n, n>=256: z_{n-256};
//                       k<256 from Wx row n, k>=256 from Wh row n.
//   [262144, 327680):   Bxn [j=256][k=256]  = Wx row 512+j
//   [327680, 393216):   Bgn [j=256][k=256]  = Wh row 512+j
// ---------------------------------------------------------------------------
__global__ void k_prep_desc(const float* __restrict__ Wx, const float* __restrict__ Wh,
                            _Float16* __restrict__ Bd) {
  int i = blockIdx.x*256 + threadIdx.x;     // 786432 total
  int dir = i / 393216;
  int rem = i % 393216;
  float v;
  if (rem < 262144) {
    int n = rem >> 9, k = rem & 511;
    v = (k < 256) ? Wx[(dir*768 + n)*256 + k] : Wh[(dir*768 + n)*256 + (k-256)];
  } else if (rem < 327680) {
    int r2 = rem - 262144; int j = r2 >> 8, k = r2 & 255;
    v = Wx[(dir*768 + 512 + j)*256 + k];
  } else {
    int r2 = rem - 327680; int j = r2 >> 8, k = r2 & 255;
    v = Wh[(dir*768 + 512 + j)*256 + k];
  }
  Bd[i] = (_Float16)v;
}

// ---------------------------------------------------------------------------
// Question GRU step (fp32, unchanged — tiny).
// ---------------------------------------------------------------------------
__global__ __launch_bounds__(256) void k_qstep(
    const int* __restrict__ tokens, const float* __restrict__ emb,
    const float* __restrict__ Wc, const float* __restrict__ bx, const float* __restrict__ bh,
    const float* __restrict__ h_in, float* __restrict__ h_out, float* __restrict__ hs,
    int step)
{
  int dir = blockIdx.z;
  int l = dir ? (QL_-1-step) : step;
  int tid = threadIdx.x;
  __shared__ float4 A4[16*128];
  __shared__ float  gl[16*64];
  const float* hi = h_in + dir*(16*256);

  for (int f = tid; f < 2048; f += 256) {
    int m = f >> 7, c4 = f & 127;
    float4 v;
    if (c4 < 64) {
      int tk = tokens[m*QL_ + l];
      v = ((const float4*)emb)[(size_t)tk*64 + c4];
    } else {
      v = ((const float4*)hi)[m*64 + (c4-64)];
    }
    A4[m*128 + c4] = v;
  }
  __syncthreads();

  int nl = tid & 63, mg = tid >> 6;
  int piece = nl >> 4, jj = nl & 15;
  int j0 = blockIdx.y*16;
  int n = piece*256 + j0 + jj;
  const float* bxd = bx + dir*768;
  const float* bhd = bh + dir*768;
  float bias = gate_bias(n, bxd, bhd);
  float acc0=bias, acc1=bias, acc2=bias, acc3=bias;
  const float* W = Wc + dir*(512*1024);
  for (int k = 0; k < 512; k += 4) {
    float w0 = W[(k+0)*1024 + n];
    float w1 = W[(k+1)*1024 + n];
    float w2 = W[(k+2)*1024 + n];
    float w3 = W[(k+3)*1024 + n];
    int kc = k >> 2;
    float4 a0 = A4[(mg*4+0)*128 + kc];
    float4 a1 = A4[(mg*4+1)*128 + kc];
    float4 a2 = A4[(mg*4+2)*128 + kc];
    float4 a3 = A4[(mg*4+3)*128 + kc];
    acc0 += a0.x*w0 + a0.y*w1 + a0.z*w2 + a0.w*w3;
    acc1 += a1.x*w0 + a1.y*w1 + a1.z*w2 + a1.w*w3;
    acc2 += a2.x*w0 + a2.y*w1 + a2.z*w2 + a2.w*w3;
    acc3 += a3.x*w0 + a3.y*w1 + a3.z*w2 + a3.w*w3;
  }
  gl[(mg*4+0)*64 + nl] = acc0;
  gl[(mg*4+1)*64 + nl] = acc1;
  gl[(mg*4+2)*64 + nl] = acc2;
  gl[(mg*4+3)*64 + nl] = acc3;
  __syncthreads();

  int m = tid >> 4, j2 = tid & 15;
  int j = j0 + j2;
  float r  = sigf(gl[m*64 + j2]);
  float z  = sigf(gl[m*64 + 16 + j2]);
  float xn = gl[m*64 + 32 + j2];
  float gn = gl[m*64 + 48 + j2];
  float nt = tanhf(xn + r*gn);
  float hold = hi[m*256 + j];
  float hn = (1.f - z)*nt + z*hold;
  int tk = tokens[m*QL_ + l];
  float hnew = (tk != 0) ? hn : hold;
  h_out[dir*(16*256) + m*256 + j] = hnew;
  hs[((dir*16 + m)*QL_ + l)*256 + j] = hnew;
}

// ---------------------------------------------------------------------------
// Persistent desc-GRU, fp16 MFMA. grid (500, 1, 2 dirs), block 256 = 4 waves.
// Block owns 32 sequences for all 12 steps; h lives in LDS as fp16 (the
// A-operand of the next step). Wave w owns hidden units j in [64w, 64w+64):
// computes r,z (K=512 over [x|h]), xn (K=256 over x), ghn (K=256 over h) for
// those units -> gate epilogue is pure per-lane register math (all four gate
// values for (m,j) sit at the same (lane,reg) slot of 4 acc fragments).
// A row stride 536 fp16 (1072 B): bank step 12 -> 2-way aliasing only (free).
// ---------------------------------------------------------------------------
__global__ __launch_bounds__(256, 2) void k_desc_gru(
    const int* __restrict__ desc, const float* __restrict__ emb,
    const _Float16* __restrict__ Bd, const float* __restrict__ bx,
    const float* __restrict__ bh, float* __restrict__ dh)
{
  const int dir  = blockIdx.z;
  const int seq0 = blockIdx.x * 32;
  const int tid  = threadIdx.x;
  const int lane = tid & 63, w = tid >> 6;
  const int lm = lane & 15, lq = lane >> 4;
  const int j0 = w * 64;

  __shared__ _Float16 A2[32*536];     // [row][ x(256) | h(256) ], padded
  __shared__ float    biasL[1024];    // [br|bz|bxn|bhn] x 256
  __shared__ int      tokL[2][32];

  // biases (constant across steps)
  {
    int i = tid;           // 256 threads x 4
    for (int rep = 0; rep < 4; ++rep, i += 256) {
      int j = i & 255, wch = i >> 8;
      float v;
      if      (wch == 0) v = bx[dir*768 + j]       + bh[dir*768 + j];
      else if (wch == 1) v = bx[dir*768 + 256 + j] + bh[dir*768 + 256 + j];
      else if (wch == 2) v = bx[dir*768 + 512 + j];
      else               v = bh[dir*768 + 512 + j];
      biasL[i] = v;
    }
  }
  // h = 0
  for (int i = tid; i < 1024; i += 256) {
    int row = i >> 5, c8 = i & 31;
    half8 z8 = {0,0,0,0,0,0,0,0};
    *(half8*)&A2[row*536 + 256 + c8*8] = z8;
  }

  const int l0 = dir ? (DL_-1) : 0;
  const int dl = dir ? -1 : 1;

  // stage x(l) + tokens(l) into parity par
  auto stage = [&](int ll, int par) {
    int row = tid >> 3, c = tid & 7;          // 8 threads/row, 32 floats each
    int s = seq0 + row;
    int tk = desc[(size_t)s*DL_ + ll];
    if (c == 0) tokL[par][row] = tk;
    const float4* src = (const float4*)(emb + (size_t)tk*256) + c*8;
    _Float16* dst = &A2[row*536 + c*32];
    #pragma unroll
    for (int q8 = 0; q8 < 4; ++q8) {
      float4 v0 = src[q8*2], v1 = src[q8*2+1];
      half8 hv;
      hv[0]=(_Float16)v0.x; hv[1]=(_Float16)v0.y; hv[2]=(_Float16)v0.z; hv[3]=(_Float16)v0.w;
      hv[4]=(_Float16)v1.x; hv[5]=(_Float16)v1.y; hv[6]=(_Float16)v1.z; hv[7]=(_Float16)v1.w;
      *(half8*)(dst + q8*8) = hv;
    }
  };
  stage(l0, 0);

  const _Float16* Bdir = Bd + (size_t)dir * 393216;
  const _Float16* Brz  = Bdir;
  const _Float16* Bxn  = Bdir + 262144;
  const _Float16* Bgn  = Bdir + 327680;
  const _Float16* A2x  = &A2[lm*536];
  const _Float16* A2y  = &A2[(16+lm)*536];

  int l = l0;
  for (int t = 0; t < DL_; ++t, l += dl) {
    __syncthreads();   // staging/h-writes visible

    floatx4 accR[2][4], accZ[2][4], accN[2][4], accG[2][4];
    #pragma unroll
    for (int a = 0; a < 2; ++a)
      #pragma unroll
      for (int b2 = 0; b2 < 4; ++b2) {
        floatx4 z4 = {0.f,0.f,0.f,0.f};
        accR[a][b2]=z4; accZ[a][b2]=z4; accN[a][b2]=z4; accG[a][b2]=z4;
      }

    // r,z: A=[x|h] K=512
    #pragma unroll 4
    for (int kf = 0; kf < 16; ++kf) {
      int k0 = kf*32 + lq*8;
      half8 a0 = *(const half8*)(A2x + k0);
      half8 a1 = *(const half8*)(A2y + k0);
      const _Float16* bp = Brz + (size_t)(j0 + lm)*512 + k0;
      #pragma unroll
      for (int t4 = 0; t4 < 4; ++t4) {
        half8 br = *(const half8*)(bp + (size_t)(t4*16)*512);
        half8 bz = *(const half8*)(bp + (size_t)(256 + t4*16)*512);
        accR[0][t4] = __builtin_amdgcn_mfma_f32_16x16x32_f16(a0, br, accR[0][t4], 0,0,0);
        accR[1][t4] = __builtin_amdgcn_mfma_f32_16x16x32_f16(a1, br, accR[1][t4], 0,0,0);
        accZ[0][t4] = __builtin_amdgcn_mfma_f32_16x16x32_f16(a0, bz, accZ[0][t4], 0,0,0);
        accZ[1][t4] = __builtin_amdgcn_mfma_f32_16x16x32_f16(a1, bz, accZ[1][t4], 0,0,0);
      }
    }
    // xn: A=x K=256
    #pragma unroll 4
    for (int kf = 0; kf < 8; ++kf) {
      int k0 = kf*32 + lq*8;
      half8 a0 = *(const half8*)(A2x + k0);
      half8 a1 = *(const half8*)(A2y + k0);
      const _Float16* bp = Bxn + (size_t)(j0 + lm)*256 + k0;
      #pragma unroll
      for (int t4 = 0; t4 < 4; ++t4) {
        half8 bn = *(const half8*)(bp + (size_t)(t4*16)*256);
        accN[0][t4] = __builtin_amdgcn_mfma_f32_16x16x32_f16(a0, bn, accN[0][t4], 0,0,0);
        accN[1][t4] = __builtin_amdgcn_mfma_f32_16x16x32_f16(a1, bn, accN[1][t4], 0,0,0);
      }
    }
    // ghn: A=h K=256
    #pragma unroll 4
    for (int kf = 0; kf < 8; ++kf) {
      int k0 = kf*32 + lq*8;
      half8 a0 = *(const half8*)(A2x + 256 + k0);
      half8 a1 = *(const half8*)(A2y + 256 + k0);
      const _Float16* bp = Bgn + (size_t)(j0 + lm)*256 + k0;
      #pragma unroll
      for (int t4 = 0; t4 < 4; ++t4) {
        half8 bg = *(const half8*)(bp + (size_t)(t4*16)*256);
        accG[0][t4] = __builtin_amdgcn_mfma_f32_16x16x32_f16(a0, bg, accG[0][t4], 0,0,0);
        accG[1][t4] = __builtin_amdgcn_mfma_f32_16x16x32_f16(a1, bg, accG[1][t4], 0,0,0);
      }
    }

    __syncthreads();   // all A2 reads done

    // prefetch next x while epilogue computes
    if (t < DL_-1) stage(l + dl, (t+1) & 1);

    int par = t & 1;
    #pragma unroll
    for (int mi = 0; mi < 2; ++mi)
      #pragma unroll
      for (int t4 = 0; t4 < 4; ++t4) {
        int j = j0 + t4*16 + lm;
        float br_ = biasL[j], bz_ = biasL[256+j], bn_ = biasL[512+j], bg_ = biasL[768+j];
        #pragma unroll
        for (int reg = 0; reg < 4; ++reg) {
          int m = mi*16 + lq*4 + reg;
          float r  = sigf(accR[mi][t4][reg] + br_);
          float z  = sigf(accZ[mi][t4][reg] + bz_);
          float nt = tanhf(accN[mi][t4][reg] + bn_ + r*(accG[mi][t4][reg] + bg_));
          float hold = (float)A2[m*536 + 256 + j];
          float hn = (1.f - z)*nt + z*hold;
          float hnew = (tokL[par][m] != 0) ? hn : hold;
          A2[m*536 + 256 + j] = (_Float16)hnew;
          if (t == DL_-1)
            dh[((size_t)dir*NSEQD + seq0 + m)*256 + j] = hnew;
        }
      }
  }
}

// q_emb = concat(hT_f, hT_b)
__global__ void k_qemb(const float* __restrict__ h0, float* __restrict__ qemb){
  int o = blockIdx.x*256 + threadIdx.x;
  int b = o >> 9, c = o & 511;
  qemb[o] = (c < 256) ? h0[b*256 + c] : h0[16*256 + b*256 + (c-256)];
}

// q_word_h = concat(hs_f, hs_b) * mask
__global__ void k_qwh(const float* __restrict__ hs, const int* __restrict__ tokens,
                      float* __restrict__ qwh){
  int o = blockIdx.x*256 + threadIdx.x;
  int b = o >> 14;
  int rem = o & 16383;
  int l = rem >> 9, c = rem & 511;
  int cc = c & 255, dirn = c >> 8;
  float v = hs[((dirn*16 + b)*QL_ + l)*256 + cc];
  float msk = (tokens[b*QL_ + l] != 0) ? 1.f : 0.f;
  qwh[o] = v * msk;
}

__global__ __launch_bounds__(256) void k_attn(
    const float* __restrict__ qemb, const float* __restrict__ qwh,
    const float* __restrict__ sW, const float* __restrict__ sb,
    const float* __restrict__ relW, float* __restrict__ u, int t)
{
  int b = blockIdx.x, tid = threadIdx.x;
  __shared__ float qe[512];
  __shared__ float cq[512];
  __shared__ float lg[32];
  __shared__ float dist[32];
  qe[tid]     = qemb[b*512 + tid];
  qe[tid+256] = qemb[b*512 + 256 + tid];
  __syncthreads();
  const float4* qe4 = (const float4*)qe;
  for (int nn = 0; nn < 2; ++nn) {
    int n = tid + nn*256;
    const float4* w4 = (const float4*)(sW + ((size_t)t*512 + n)*512);
    float acc = 0.f;
    for (int k4 = 0; k4 < 128; ++k4) {
      float4 w = w4[k4]; float4 q = qe4[k4];
      acc += w.x*q.x + w.y*q.y + w.z*q.z + w.w*q.w;
    }
    cq[n] = tanhf(acc + sb[t*512 + n]);
  }
  __syncthreads();
  if (tid < 32) {
    const float4* r4 = (const float4*)(qwh + ((size_t)b*QL_ + tid)*512);
    const float4* c4 = (const float4*)cq;
    float acc = 0.f;
    for (int k4 = 0; k4 < 128; ++k4) {
      float4 w = r4[k4]; float4 q = c4[k4];
      acc += w.x*q.x + w.y*q.y + w.z*q.z + w.w*q.w;
    }
    lg[tid] = acc;
  }
  __syncthreads();
  if (tid == 0) {
    float mx = lg[0];
    for (int i = 1; i < 32; ++i) mx = fmaxf(mx, lg[i]);
    float s = 0.f;
    for (int i = 0; i < 32; ++i) { float e = expf(lg[i]-mx); dist[i] = e; s += e; }
    float inv = 1.f/s;
    for (int i = 0; i < 32; ++i) dist[i] *= inv;
  }
  __syncthreads();
  for (int nn = 0; nn < 2; ++nn) {
    int c = tid + nn*256;
    float acc = 0.f;
    #pragma unroll 4
    for (int ll = 0; ll < 32; ++ll)
      acc += dist[ll] * qwh[((size_t)b*QL_ + ll)*512 + c];
    u[b*512 + c] = acc * relW[c];
  }
}

__global__ __launch_bounds__(256) void k_dlogit(
    const float* __restrict__ u, const float* __restrict__ dh,
    const float* __restrict__ relb, float* __restrict__ dprob, int t)
{
  int w = threadIdx.x >> 6, lane = threadIdx.x & 63;
  int o = blockIdx.x*4 + w;
  int b = o / 500;
  int s = t*(B_*RSZ_) + o;
  const float* e0 = dh + (size_t)s*256;
  const float* e1 = dh + (size_t)NSEQD*256 + (size_t)s*256;
  float acc = 0.f;
  #pragma unroll
  for (int i = 0; i < 4; ++i) {
    int c = lane + i*64;
    acc += u[b*512 + c]       * e0[c];
    acc += u[b*512 + 256 + c] * e1[c];
  }
  #pragma unroll
  for (int off = 32; off; off >>= 1) acc += __shfl_down(acc, off);
  if (lane == 0) dprob[o] = sigf(acc + relb[0]);
}

__global__ void k_scatter(const int* __restrict__ pair, const float* __restrict__ dprob,
                          const float* __restrict__ esrc, float* __restrict__ edst,
                          int t, int clampflag)
{
  int o = blockIdx.x*256 + threadIdx.x;
  if (o >= B_*RSZ_) return;
  int b = o / RSZ_, r = o % RSZ_;
  const int* pp = pair + (((size_t)t*B_ + b)*RSZ_ + r)*2;
  int sub = pp[0], obj = pp[1];
  float v = esrc[(size_t)b*NE_ + sub];
  if (clampflag) v = fminf(v, 1.0f);
  atomicAdd(edst + (size_t)b*NE_ + obj, v * dprob[o]);
}

__global__ __launch_bounds__(256) void k_final(
    const float* __restrict__ qemb, const float* __restrict__ W,
    const float* __restrict__ bias, const float* __restrict__ efin,
    float* __restrict__ out)
{
  int tid = threadIdx.x;
  int lane = tid & 63;
  int ks = lane & 15, bg = lane >> 4;
  int b = (tid >> 6)*4 + bg;
  float q[32];
  {
    const float4* q4 = (const float4*)(qemb + b*512 + ks*32);
    #pragma unroll
    for (int i = 0; i < 8; ++i) {
      float4 v = q4[i];
      q[4*i]=v.x; q[4*i+1]=v.y; q[4*i+2]=v.z; q[4*i+3]=v.w;
    }
  }
  int e0 = blockIdx.x*256;
  int eend = (e0+256 < NE_) ? e0+256 : NE_;
  for (int e = e0; e < eend; ++e) {
    const float4* w4 = (const float4*)(W + (size_t)e*512 + ks*32);
    float acc = 0.f;
    #pragma unroll
    for (int i = 0; i < 8; ++i) {
      float4 v = w4[i];
      acc += v.x*q[4*i] + v.y*q[4*i+1] + v.z*q[4*i+2] + v.w*q[4*i+3];
    }
    acc += __shfl_xor(acc, 1);
    acc += __shfl_xor(acc, 2);
    acc += __shfl_xor(acc, 4);
    acc += __shfl_xor(acc, 8);
    if (ks == 0) {
      float msk = sigf(acc + bias[e]);
      float ev = fminf(efin[(size_t)b*NE_ + e], 1.0f);
      out[(size_t)b*NE_ + e] = ev * msk;
    }
  }
}

extern "C" void kernel_launch(void* const* d_in, const int* in_sizes, int n_in,
                              void* d_out, int out_size, void* d_ws, size_t ws_size,
                              hipStream_t stream)
{
  const int*   questions = (const int*)d_in[0];
  const float* e_s   = (const float*)d_in[1];
  const int*   pair  = (const int*)d_in[2];
  const int*   desc  = (const int*)d_in[3];
  const float* emb   = (const float*)d_in[4];
  const float* qWx   = (const float*)d_in[5];
  const float* qWh   = (const float*)d_in[6];
  const float* qbx   = (const float*)d_in[7];
  const float* qbh   = (const float*)d_in[8];
  const float* dWx   = (const float*)d_in[9];
  const float* dWh   = (const float*)d_in[10];
  const float* dbx   = (const float*)d_in[11];
  const float* dbh   = (const float*)d_in[12];
  const float* stepW = (const float*)d_in[13];
  const float* stepb = (const float*)d_in[14];
  const float* relW  = (const float*)d_in[15];
  const float* relb  = (const float*)d_in[16];
  const float* qclsW = (const float*)d_in[17];
  const float* qclsb = (const float*)d_in[18];
  float* out = (float*)d_out;

  char* ws = (char*)d_ws;
  size_t off = 0;
  auto alloc = [&](size_t bytes)->void* {
    void* p = ws + off; off += (bytes + 255) & ~(size_t)255; return p;
  };
  float*     WcQ  = (float*)alloc((size_t)2*512*1024*sizeof(float));   // 4 MB
  _Float16*  Bd   = (_Float16*)alloc((size_t)2*393216*sizeof(_Float16)); // 1.5 MB
  float* qh   = (float*)alloc((size_t)2*2*16*256*sizeof(float));
  float* qhs  = (float*)alloc((size_t)2*16*QL_*256*sizeof(float));
  float* qemb = (float*)alloc((size_t)16*512*sizeof(float));
  float* qwh  = (float*)alloc((size_t)16*QL_*512*sizeof(float));
  float* dh   = (float*)alloc((size_t)2*NSEQD*256*sizeof(float));      // 32.8 MB
  float* u    = (float*)alloc((size_t)16*512*sizeof(float));
  float* dprob= (float*)alloc((size_t)B_*RSZ_*sizeof(float));
  float* ebuf = (float*)alloc((size_t)2*B_*NE_*sizeof(float));         // 12.8 MB

  hipMemsetAsync(qh,   0, (size_t)2*2*16*256*sizeof(float), stream);
  hipMemsetAsync(ebuf, 0, (size_t)2*B_*NE_*sizeof(float), stream);

  k_build_comb<<<4096, 256, 0, stream>>>(qWx, qWh, WcQ);
  k_prep_desc<<<3072, 256, 0, stream>>>(dWx, dWh, Bd);

  for (int s = 0; s < QL_; ++s) {
    const float* hin = qh + (size_t)(s & 1)*(2*16*256);
    float*      hout = qh + (size_t)((s+1) & 1)*(2*16*256);
    k_qstep<<<dim3(1,16,2), 256, 0, stream>>>(questions, emb, WcQ, qbx, qbh, hin, hout, qhs, s);
  }
  k_qemb<<<32, 256, 0, stream>>>(qh, qemb);
  k_qwh<<<1024, 256, 0, stream>>>(qhs, questions, qwh);

  // persistent fp16-MFMA desc GRU: all 12 steps in one launch
  k_desc_gru<<<dim3(500,1,2), 256, 0, stream>>>(desc, emb, Bd, dbx, dbh, dh);

  for (int t = 0; t < T_; ++t) {
    k_attn<<<16, 256, 0, stream>>>(qemb, qwh, stepW, stepb, relW, u, t);
    k_dlogit<<<2000, 256, 0, stream>>>(u, dh, relb, dprob, t);
    const float* esrc = (t == 0) ? e_s : ebuf;
    float* edst = ebuf + (size_t)t*B_*NE_;
    k_scatter<<<32, 256, 0, stream>>>(pair, dprob, esrc, edst, t, t);
  }
  k_final<<<(NE_+255)/256, 256, 0, stream>>>(qemb, qclsW, qclsb, ebuf + (size_t)B_*NE_, out);
}

// Round 3
// 2059.384 us; speedup vs baseline: 3.4464x; 1.3037x over previous
//
#include <hip/hip_runtime.h>
#include <math.h>

#define B_    16
#define QL_   32
#define DL_   12
#define RSZ_  500
#define T_    2
#define DW_   256
#define DH_   512
#define HP_   256
#define NW_   50000
#define NE_   100000
#define NSEQD (T_*B_*RSZ_)   // 16000

typedef _Float16 half8 __attribute__((ext_vector_type(8)));
typedef float   floatx4 __attribute__((ext_vector_type(4)));

__device__ __forceinline__ float sigf(float x){ return 1.0f/(1.0f+expf(-x)); }

// ---------------------------------------------------------------------------
// Desc-GRU fp16 B^T weights. Per dir (393216 elems):
//   [0, 262144):        Brz [n=512][k=512]  n<256: r_n, n>=256: z_{n-256};
//                       k<256 from Wx row n, k>=256 from Wh row n.
//   [262144, 327680):   Bxn [j=256][k=256]  = Wx row 512+j
//   [327680, 393216):   Bgn [j=256][k=256]  = Wh row 512+j
// ---------------------------------------------------------------------------
__global__ void k_prep_desc(const float* __restrict__ Wx, const float* __restrict__ Wh,
                            _Float16* __restrict__ Bd) {
  int i = blockIdx.x*256 + threadIdx.x;     // 786432 total
  int dir = i / 393216;
  int rem = i % 393216;
  float v;
  if (rem < 262144) {
    int n = rem >> 9, k = rem & 511;
    v = (k < 256) ? Wx[(dir*768 + n)*256 + k] : Wh[(dir*768 + n)*256 + (k-256)];
  } else if (rem < 327680) {
    int r2 = rem - 262144; int j = r2 >> 8, k = r2 & 255;
    v = Wx[(dir*768 + 512 + j)*256 + k];
  } else {
    int r2 = rem - 327680; int j = r2 >> 8, k = r2 & 255;
    v = Wh[(dir*768 + 512 + j)*256 + k];
  }
  Bd[i] = (_Float16)v;
}

// q-GRU recurrent weight fp32 -> fp16, same [dir][768][256] layout
__global__ void k_prep_qwh(const float* __restrict__ Wh, _Float16* __restrict__ WhQ) {
  int i = blockIdx.x*256 + threadIdx.x;     // 393216
  WhQ[i] = (_Float16)Wh[i];
}

// ---------------------------------------------------------------------------
// Q-GRU x-projection: xp[dir][b][l][n] = emb[questions[b][l]] . qWx[dir][n][:] + qbx[dir][n]
// grid (16 b, 6 n-tiles of 128, 2 dir), block 256.
// ---------------------------------------------------------------------------
__global__ __launch_bounds__(256) void k_xproj(
    const int* __restrict__ questions, const float* __restrict__ emb,
    const float* __restrict__ Wx, const float* __restrict__ bx,
    float* __restrict__ xp)
{
  int b = blockIdx.x, n0 = blockIdx.y*128, dir = blockIdx.z;
  int tid = threadIdx.x;
  __shared__ float As[32*256];
  {
    int l = tid >> 3, c8 = tid & 7;
    int tk = questions[b*QL_ + l];
    const float4* src = (const float4*)(emb + (size_t)tk*256) + c8*8;
    float4* dst = (float4*)(As + l*256 + c8*32);
    #pragma unroll
    for (int q = 0; q < 8; ++q) dst[q] = src[q];
  }
  __syncthreads();
  int rr = tid >> 7, jj = tid & 127;
  int n = n0 + jj;
  const float4* W4 = (const float4*)(Wx + ((size_t)dir*768 + n)*256);
  const float4* A4 = (const float4*)As;
  float acc[16];
  #pragma unroll
  for (int i = 0; i < 16; ++i) acc[i] = 0.f;
  for (int k4 = 0; k4 < 64; ++k4) {
    float4 wv = W4[k4];
    #pragma unroll
    for (int i = 0; i < 16; ++i) {
      float4 av = A4[(rr*16 + i)*64 + k4];
      acc[i] += av.x*wv.x + av.y*wv.y + av.z*wv.z + av.w*wv.w;
    }
  }
  float bias = bx[dir*768 + n];
  for (int i = 0; i < 16; ++i)
    xp[(((size_t)dir*16 + b)*QL_ + rr*16 + i)*768 + n] = acc[i] + bias;
}

// ---------------------------------------------------------------------------
// Persistent q-GRU: grid (2 dirs), block 512 = 8 waves. Wh fp16 held in
// 192 VGPRs/wave (48 b128 frags); h in 8 KB swizzled LDS (fp16, the MFMA A
// operand) + fp32 in regs. Wave w owns j-slice [32w, 32w+32) for r,z,ghn.
// D layout: row(lq*4+reg)=m=b, col(lm)=n=j.
// ---------------------------------------------------------------------------
__global__ __launch_bounds__(512, 2) void k_qgru(
    const int* __restrict__ questions, const _Float16* __restrict__ WhQ,
    const float* __restrict__ bh, const float* __restrict__ xp,
    float* __restrict__ qwh, float* __restrict__ qemb)
{
  const int dir = blockIdx.x;
  const int tid = threadIdx.x;
  const int lane = tid & 63, w = tid >> 6;
  const int lm = lane & 15, lq = lane >> 4;
  const int j0 = w * 32;

  __shared__ _Float16 hA[16*256];   // swizzled: chunk p = c ^ row
  __shared__ int tokS[16*QL_];

  tokS[tid] = questions[tid];
  {
    int row = tid >> 5, c = tid & 31;
    half8 z8 = {0,0,0,0,0,0,0,0};
    *(half8*)(hA + row*256 + (c ^ row)*8) = z8;
  }

  // preload Wh fragments: Bq[gate][f][kf]
  half8 Bq[3][2][8];
  #pragma unroll
  for (int g = 0; g < 3; ++g)
    #pragma unroll
    for (int f = 0; f < 2; ++f)
      #pragma unroll
      for (int kf = 0; kf < 8; ++kf) {
        int row = g*256 + j0 + f*16 + lm;
        Bq[g][f][kf] = *(const half8*)(WhQ + ((size_t)dir*768 + row)*256 + kf*32 + lq*8);
      }
  float bh_r[2], bh_z[2], bh_n[2];
  #pragma unroll
  for (int f = 0; f < 2; ++f) {
    int j = j0 + f*16 + lm;
    bh_r[f] = bh[dir*768 + j];
    bh_z[f] = bh[dir*768 + 256 + j];
    bh_n[f] = bh[dir*768 + 512 + j];
  }
  float hreg[2][4];
  #pragma unroll
  for (int f = 0; f < 2; ++f)
    #pragma unroll
    for (int r = 0; r < 4; ++r) hreg[f][r] = 0.f;

  __syncthreads();

  for (int t = 0; t < QL_; ++t) {
    int l = dir ? (QL_-1-t) : t;
    floatx4 aR[2], aZ[2], aG[2];
    #pragma unroll
    for (int f = 0; f < 2; ++f) {
      floatx4 z4 = {0.f,0.f,0.f,0.f};
      aR[f]=z4; aZ[f]=z4; aG[f]=z4;
    }
    #pragma unroll
    for (int kf = 0; kf < 8; ++kf) {
      int p = (kf*4 + lq) ^ lm;
      half8 a = *(const half8*)(hA + lm*256 + p*8);
      #pragma unroll
      for (int f = 0; f < 2; ++f) {
        aR[f] = __builtin_amdgcn_mfma_f32_16x16x32_f16(a, Bq[0][f][kf], aR[f], 0,0,0);
        aZ[f] = __builtin_amdgcn_mfma_f32_16x16x32_f16(a, Bq[1][f][kf], aZ[f], 0,0,0);
        aG[f] = __builtin_amdgcn_mfma_f32_16x16x32_f16(a, Bq[2][f][kf], aG[f], 0,0,0);
      }
    }
    __syncthreads();   // MFMA reads of hA done

    #pragma unroll
    for (int f = 0; f < 2; ++f) {
      int j = j0 + f*16 + lm;
      #pragma unroll
      for (int reg = 0; reg < 4; ++reg) {
        int b = lq*4 + reg;
        const float* xpb = xp + (((size_t)dir*16 + b)*QL_ + l)*768;
        float r  = sigf(xpb[j]       + aR[f][reg] + bh_r[f]);
        float z  = sigf(xpb[256 + j] + aZ[f][reg] + bh_z[f]);
        float nt = tanhf(xpb[512 + j] + r*(aG[f][reg] + bh_n[f]));
        float hold = hreg[f][reg];
        float hn = (1.f - z)*nt + z*hold;
        int tk = tokS[b*QL_ + l];
        float hnew = (tk != 0) ? hn : hold;
        hreg[f][reg] = hnew;
        int p2 = ((j >> 3) ^ b);
        hA[b*256 + p2*8 + (j & 7)] = (_Float16)hnew;
        qwh[((size_t)b*QL_ + l)*512 + dir*256 + j] = (tk != 0) ? hnew : 0.f;
      }
    }
    __syncthreads();   // h writes visible
  }
  #pragma unroll
  for (int f = 0; f < 2; ++f) {
    int j = j0 + f*16 + lm;
    #pragma unroll
    for (int reg = 0; reg < 4; ++reg) {
      int b = lq*4 + reg;
      qemb[b*512 + dir*256 + j] = hreg[f][reg];
    }
  }
}

// ---------------------------------------------------------------------------
// Persistent desc-GRU v2. grid (250, 1, 2), block 1024 = 16 waves, M=64 seqs.
// LDS: A2 = 64 rows x 512 fp16 [x(256)|h(256)], XOR-swizzled 16B chunks
// (p = c ^ row) -> conflict-free b128 access, exactly 64 KB static.
// Wave w owns j-slice [16w, 16w+16): acc[4 m][4 gates] = 64 VGPRs.
// A-frag read once per (mi,kf), used for 3 MFMAs (r, z, xn|ghn).
// Per-block k-stagger (rot) decorrelates L2 channels across blocks.
// ---------------------------------------------------------------------------
__global__ __launch_bounds__(1024, 4) void k_desc_gru(
    const int* __restrict__ desc, const float* __restrict__ emb,
    const _Float16* __restrict__ Bd, const float* __restrict__ bx,
    const float* __restrict__ bh, float* __restrict__ dh)
{
  const int dir  = blockIdx.z;
  const int seq0 = blockIdx.x * 64;
  const int tid  = threadIdx.x;
  const int lane = tid & 63, w = tid >> 6;
  const int lm = lane & 15, lq = lane >> 4;
  const int j0 = w * 16;
  const int rot = blockIdx.x & 7;

  __shared__ _Float16 A2[64*512];   // 64 KB, swizzled

  // zero h region (chunks 32..63 per row)
  {
    int row = tid >> 4, cc = tid & 15;
    half8 z8 = {0,0,0,0,0,0,0,0};
    #pragma unroll
    for (int q = 0; q < 2; ++q) {
      int c = 32 + cc*2 + q;
      *(half8*)(A2 + row*512 + (c ^ row)*8) = z8;
    }
  }

  const int l0 = dir ? (DL_-1) : 0;
  const int dl = dir ? -1 : 1;

  auto stage_x = [&](int ll) {
    int row = tid >> 4, cc = tid & 15;
    int s = seq0 + row;
    int tk = desc[(size_t)s*DL_ + ll];
    const float4* src = (const float4*)(emb + (size_t)tk*256);
    #pragma unroll
    for (int q = 0; q < 2; ++q) {
      int c = cc*2 + q;
      float4 v0 = src[c*2], v1 = src[c*2+1];
      half8 hv;
      hv[0]=(_Float16)v0.x; hv[1]=(_Float16)v0.y; hv[2]=(_Float16)v0.z; hv[3]=(_Float16)v0.w;
      hv[4]=(_Float16)v1.x; hv[5]=(_Float16)v1.y; hv[6]=(_Float16)v1.z; hv[7]=(_Float16)v1.w;
      *(half8*)(A2 + row*512 + (c ^ row)*8) = hv;
    }
  };
  stage_x(l0);

  const _Float16* Bdir = Bd + (size_t)dir * 393216;
  const _Float16* Brz  = Bdir;
  const _Float16* Bxn  = Bdir + 262144;
  const _Float16* Bgn  = Bdir + 327680;

  // per-lane biases (j = j0 + lm fixed for this lane)
  const int jl = j0 + lm;
  const float bias_r = bx[dir*768 + jl]       + bh[dir*768 + jl];
  const float bias_z = bx[dir*768 + 256 + jl] + bh[dir*768 + 256 + jl];
  const float bias_n = bx[dir*768 + 512 + jl];
  const float bias_g = bh[dir*768 + 512 + jl];

  int l = l0;
  for (int t = 0; t < DL_; ++t, l += dl) {
    __syncthreads();   // staging/h-writes visible

    floatx4 accR[4], accZ[4], accN[4], accG[4];
    #pragma unroll
    for (int mi = 0; mi < 4; ++mi) {
      floatx4 z4 = {0.f,0.f,0.f,0.f};
      accR[mi]=z4; accZ[mi]=z4; accN[mi]=z4; accG[mi]=z4;
    }

    #pragma unroll
    for (int half = 0; half < 2; ++half) {
      #pragma unroll 2
      for (int kk = 0; kk < 8; ++kk) {
        int kfx = half*8 + ((kk + rot) & 7);
        int k0 = kfx*32 + lq*8;
        half8 br = *(const half8*)(Brz + (size_t)jl*512 + k0);
        half8 bz = *(const half8*)(Brz + (size_t)(256 + jl)*512 + k0);
        half8 bb = half ? *(const half8*)(Bgn + (size_t)jl*256 + (k0 - 256))
                        : *(const half8*)(Bxn + (size_t)jl*256 + k0);
        int cb = kfx*4 + lq;
        #pragma unroll
        for (int mi = 0; mi < 4; ++mi) {
          int row = mi*16 + lm;
          half8 a = *(const half8*)(A2 + row*512 + (cb ^ row)*8);
          accR[mi] = __builtin_amdgcn_mfma_f32_16x16x32_f16(a, br, accR[mi], 0,0,0);
          accZ[mi] = __builtin_amdgcn_mfma_f32_16x16x32_f16(a, bz, accZ[mi], 0,0,0);
          if (half) accG[mi] = __builtin_amdgcn_mfma_f32_16x16x32_f16(a, bb, accG[mi], 0,0,0);
          else      accN[mi] = __builtin_amdgcn_mfma_f32_16x16x32_f16(a, bb, accN[mi], 0,0,0);
        }
      }
    }

    __syncthreads();   // all A2 reads done

    // epilogue: D row(lq*4+reg)=m, col(lm)=j  (round-2-verified orientation)
    #pragma unroll
    for (int mi = 0; mi < 4; ++mi) {
      #pragma unroll
      for (int reg = 0; reg < 4; ++reg) {
        int m = mi*16 + lq*4 + reg;
        float r  = sigf(accR[mi][reg] + bias_r);
        float z  = sigf(accZ[mi][reg] + bias_z);
        float nt = tanhf(accN[mi][reg] + bias_n + r*(accG[mi][reg] + bias_g));
        int c2 = 32 + (jl >> 3);
        _Float16* hp = A2 + m*512 + ((c2 ^ m)*8) + (jl & 7);
        float hold = (float)(*hp);
        float hn = (1.f - z)*nt + z*hold;
        int tk = desc[(size_t)(seq0 + m)*DL_ + l];
        float hnew = (tk != 0) ? hn : hold;
        *hp = (_Float16)hnew;
        if (t == DL_-1)
          dh[((size_t)dir*NSEQD + seq0 + m)*256 + jl] = hnew;
      }
    }
    if (t < DL_-1) stage_x(l + dl);
  }
}

// Per t: cq = tanh(q_emb @ step_W^T + b); att softmax; ctx; u = ctx*rel_W.
__global__ __launch_bounds__(256) void k_attn(
    const float* __restrict__ qemb, const float* __restrict__ qwh,
    const float* __restrict__ sW, const float* __restrict__ sb,
    const float* __restrict__ relW, float* __restrict__ u, int t)
{
  int b = blockIdx.x, tid = threadIdx.x;
  __shared__ float qe[512];
  __shared__ float cq[512];
  __shared__ float lg[32];
  __shared__ float dist[32];
  qe[tid]     = qemb[b*512 + tid];
  qe[tid+256] = qemb[b*512 + 256 + tid];
  __syncthreads();
  const float4* qe4 = (const float4*)qe;
  for (int nn = 0; nn < 2; ++nn) {
    int n = tid + nn*256;
    const float4* w4 = (const float4*)(sW + ((size_t)t*512 + n)*512);
    float acc = 0.f;
    for (int k4 = 0; k4 < 128; ++k4) {
      float4 w = w4[k4]; float4 q = qe4[k4];
      acc += w.x*q.x + w.y*q.y + w.z*q.z + w.w*q.w;
    }
    cq[n] = tanhf(acc + sb[t*512 + n]);
  }
  __syncthreads();
  if (tid < 32) {
    const float4* r4 = (const float4*)(qwh + ((size_t)b*QL_ + tid)*512);
    const float4* c4 = (const float4*)cq;
    float acc = 0.f;
    for (int k4 = 0; k4 < 128; ++k4) {
      float4 w = r4[k4]; float4 q = c4[k4];
      acc += w.x*q.x + w.y*q.y + w.z*q.z + w.w*q.w;
    }
    lg[tid] = acc;
  }
  __syncthreads();
  if (tid == 0) {
    float mx = lg[0];
    for (int i = 1; i < 32; ++i) mx = fmaxf(mx, lg[i]);
    float s = 0.f;
    for (int i = 0; i < 32; ++i) { float e = expf(lg[i]-mx); dist[i] = e; s += e; }
    float inv = 1.f/s;
    for (int i = 0; i < 32; ++i) dist[i] *= inv;
  }
  __syncthreads();
  for (int nn = 0; nn < 2; ++nn) {
    int c = tid + nn*256;
    float acc = 0.f;
    #pragma unroll 4
    for (int ll = 0; ll < 32; ++ll)
      acc += dist[ll] * qwh[((size_t)b*QL_ + ll)*512 + c];
    u[b*512 + c] = acc * relW[c];
  }
}

__global__ __launch_bounds__(256) void k_dlogit(
    const float* __restrict__ u, const float* __restrict__ dh,
    const float* __restrict__ relb, float* __restrict__ dprob, int t)
{
  int w = threadIdx.x >> 6, lane = threadIdx.x & 63;
  int o = blockIdx.x*4 + w;
  int b = o / 500;
  int s = t*(B_*RSZ_) + o;
  const float* e0 = dh + (size_t)s*256;
  const float* e1 = dh + (size_t)NSEQD*256 + (size_t)s*256;
  float acc = 0.f;
  #pragma unroll
  for (int i = 0; i < 4; ++i) {
    int c = lane + i*64;
    acc += u[b*512 + c]       * e0[c];
    acc += u[b*512 + 256 + c] * e1[c];
  }
  #pragma unroll
  for (int off = 32; off; off >>= 1) acc += __shfl_down(acc, off);
  if (lane == 0) dprob[o] = sigf(acc + relb[0]);
}

__global__ void k_scatter(const int* __restrict__ pair, const float* __restrict__ dprob,
                          const float* __restrict__ esrc, float* __restrict__ edst,
                          int t, int clampflag)
{
  int o = blockIdx.x*256 + threadIdx.x;
  if (o >= B_*RSZ_) return;
  int b = o / RSZ_, r = o % RSZ_;
  const int* pp = pair + (((size_t)t*B_ + b)*RSZ_ + r)*2;
  int sub = pp[0], obj = pp[1];
  float v = esrc[(size_t)b*NE_ + sub];
  if (clampflag) v = fminf(v, 1.0f);
  atomicAdd(edst + (size_t)b*NE_ + obj, v * dprob[o]);
}

__global__ __launch_bounds__(256) void k_final(
    const float* __restrict__ qemb, const float* __restrict__ W,
    const float* __restrict__ bias, const float* __restrict__ efin,
    float* __restrict__ out)
{
  int tid = threadIdx.x;
  int lane = tid & 63;
  int ks = lane & 15, bg = lane >> 4;
  int b = (tid >> 6)*4 + bg;
  float q[32];
  {
    const float4* q4 = (const float4*)(qemb + b*512 + ks*32);
    #pragma unroll
    for (int i = 0; i < 8; ++i) {
      float4 v = q4[i];
      q[4*i]=v.x; q[4*i+1]=v.y; q[4*i+2]=v.z; q[4*i+3]=v.w;
    }
  }
  int e0 = blockIdx.x*256;
  int eend = (e0+256 < NE_) ? e0+256 : NE_;
  for (int e = e0; e < eend; ++e) {
    const float4* w4 = (const float4*)(W + (size_t)e*512 + ks*32);
    float acc = 0.f;
    #pragma unroll
    for (int i = 0; i < 8; ++i) {
      float4 v = w4[i];
      acc += v.x*q[4*i] + v.y*q[4*i+1] + v.z*q[4*i+2] + v.w*q[4*i+3];
    }
    acc += __shfl_xor(acc, 1);
    acc += __shfl_xor(acc, 2);
    acc += __shfl_xor(acc, 4);
    acc += __shfl_xor(acc, 8);
    if (ks == 0) {
      float msk = sigf(acc + bias[e]);
      float ev = fminf(efin[(size_t)b*NE_ + e], 1.0f);
      out[(size_t)b*NE_ + e] = ev * msk;
    }
  }
}

extern "C" void kernel_launch(void* const* d_in, const int* in_sizes, int n_in,
                              void* d_out, int out_size, void* d_ws, size_t ws_size,
                              hipStream_t stream)
{
  const int*   questions = (const int*)d_in[0];
  const float* e_s   = (const float*)d_in[1];
  const int*   pair  = (const int*)d_in[2];
  const int*   desc  = (const int*)d_in[3];
  const float* emb   = (const float*)d_in[4];
  const float* qWx   = (const float*)d_in[5];
  const float* qWh   = (const float*)d_in[6];
  const float* qbx   = (const float*)d_in[7];
  const float* qbh   = (const float*)d_in[8];
  const float* dWx   = (const float*)d_in[9];
  const float* dWh   = (const float*)d_in[10];
  const float* dbx   = (const float*)d_in[11];
  const float* dbh   = (const float*)d_in[12];
  const float* stepW = (const float*)d_in[13];
  const float* stepb = (const float*)d_in[14];
  const float* relW  = (const float*)d_in[15];
  const float* relb  = (const float*)d_in[16];
  const float* qclsW = (const float*)d_in[17];
  const float* qclsb = (const float*)d_in[18];
  float* out = (float*)d_out;

  char* ws = (char*)d_ws;
  size_t off = 0;
  auto alloc = [&](size_t bytes)->void* {
    void* p = ws + off; off += (bytes + 255) & ~(size_t)255; return p;
  };
  _Float16* Bd   = (_Float16*)alloc((size_t)2*393216*sizeof(_Float16)); // 1.5 MB
  _Float16* WhQ  = (_Float16*)alloc((size_t)2*768*256*sizeof(_Float16));// 0.75 MB
  float* xp   = (float*)alloc((size_t)2*16*QL_*768*sizeof(float));      // 3.1 MB
  float* qemb = (float*)alloc((size_t)16*512*sizeof(float));
  float* qwh  = (float*)alloc((size_t)16*QL_*512*sizeof(float));        // 1 MB
  float* dh   = (float*)alloc((size_t)2*NSEQD*256*sizeof(float));       // 32.8 MB
  float* u    = (float*)alloc((size_t)16*512*sizeof(float));
  float* dprob= (float*)alloc((size_t)B_*RSZ_*sizeof(float));
  float* ebuf = (float*)alloc((size_t)2*B_*NE_*sizeof(float));          // 12.8 MB

  hipMemsetAsync(ebuf, 0, (size_t)2*B_*NE_*sizeof(float), stream);

  k_prep_desc<<<3072, 256, 0, stream>>>(dWx, dWh, Bd);
  k_prep_qwh<<<1536, 256, 0, stream>>>(qWh, WhQ);

  k_xproj<<<dim3(16,6,2), 256, 0, stream>>>(questions, emb, qWx, qbx, xp);
  k_qgru<<<2, 512, 0, stream>>>(questions, WhQ, qbh, xp, qwh, qemb);

  k_desc_gru<<<dim3(250,1,2), 1024, 0, stream>>>(desc, emb, Bd, dbx, dbh, dh);

  for (int t = 0; t < T_; ++t) {
    k_attn<<<16, 256, 0, stream>>>(qemb, qwh, stepW, stepb, relW, u, t);
    k_dlogit<<<2000, 256, 0, stream>>>(u, dh, relb, dprob, t);
    const float* esrc = (t == 0) ? e_s : ebuf;
    float* edst = ebuf + (size_t)t*B_*NE_;
    k_scatter<<<32, 256, 0, stream>>>(pair, dprob, esrc, edst, t, t);
  }
  k_final<<<(NE_+255)/256, 256, 0, stream>>>(qemb, qclsW, qclsb, ebuf + (size_t)B_*NE_, out);
}

// Round 4
// 1833.573 us; speedup vs baseline: 3.8708x; 1.1232x over previous
//
#include <hip/hip_runtime.h>
#include <math.h>

#define B_    16
#define QL_   32
#define DL_   12
#define RSZ_  500
#define T_    2
#define DW_   256
#define DH_   512
#define HP_   256
#define NW_   50000
#define NE_   100000
#define NSEQD (T_*B_*RSZ_)   // 16000

typedef _Float16 half8 __attribute__((ext_vector_type(8)));
typedef float   floatx4 __attribute__((ext_vector_type(4)));

// fast transcendentals: native v_exp_f32 / v_rcp_f32 (~1e-7 rel err, far below
// the fp16 noise floor of the GRU recurrence)
__device__ __forceinline__ float sigf(float x){
  return __builtin_amdgcn_rcpf(1.0f + __expf(-x));
}
__device__ __forceinline__ float tanhfast(float x){
  return 1.0f - 2.0f*__builtin_amdgcn_rcpf(1.0f + __expf(2.0f*x));
}

// ---------------------------------------------------------------------------
// Desc-GRU fp16 B^T weights. Per dir (393216 elems):
//   [0, 262144):        Brz [n=512][k=512]  n<256: r_n, n>=256: z_{n-256};
//                       k<256 from Wx row n, k>=256 from Wh row n.
//   [262144, 327680):   Bxn [j=256][k=256]  = Wx row 512+j
//   [327680, 393216):   Bgn [j=256][k=256]  = Wh row 512+j
// ---------------------------------------------------------------------------
__global__ void k_prep_desc(const float* __restrict__ Wx, const float* __restrict__ Wh,
                            _Float16* __restrict__ Bd) {
  int i = blockIdx.x*256 + threadIdx.x;     // 786432 total
  int dir = i / 393216;
  int rem = i % 393216;
  float v;
  if (rem < 262144) {
    int n = rem >> 9, k = rem & 511;
    v = (k < 256) ? Wx[(dir*768 + n)*256 + k] : Wh[(dir*768 + n)*256 + (k-256)];
  } else if (rem < 327680) {
    int r2 = rem - 262144; int j = r2 >> 8, k = r2 & 255;
    v = Wx[(dir*768 + 512 + j)*256 + k];
  } else {
    int r2 = rem - 327680; int j = r2 >> 8, k = r2 & 255;
    v = Wh[(dir*768 + 512 + j)*256 + k];
  }
  Bd[i] = (_Float16)v;
}

// q-GRU recurrent weight fp32 -> fp16, same [dir][768][256] layout
__global__ void k_prep_qwh(const float* __restrict__ Wh, _Float16* __restrict__ WhQ) {
  int i = blockIdx.x*256 + threadIdx.x;     // 393216
  WhQ[i] = (_Float16)Wh[i];
}

// ---------------------------------------------------------------------------
// Q-GRU x-projection. NEW layout: xp[dir][l][b][768] so the recurrence can
// stage one (dir,l) slab (16x768 fp32 = 48 KB) with fully coalesced loads.
// grid (16 b, 6 n-tiles of 128, 2 dir), block 256.
// ---------------------------------------------------------------------------
__global__ __launch_bounds__(256) void k_xproj(
    const int* __restrict__ questions, const float* __restrict__ emb,
    const float* __restrict__ Wx, const float* __restrict__ bx,
    float* __restrict__ xp)
{
  int b = blockIdx.x, n0 = blockIdx.y*128, dir = blockIdx.z;
  int tid = threadIdx.x;
  __shared__ float As[32*256];
  {
    int l = tid >> 3, c8 = tid & 7;
    int tk = questions[b*QL_ + l];
    const float4* src = (const float4*)(emb + (size_t)tk*256) + c8*8;
    float4* dst = (float4*)(As + l*256 + c8*32);
    #pragma unroll
    for (int q = 0; q < 8; ++q) dst[q] = src[q];
  }
  __syncthreads();
  int rr = tid >> 7, jj = tid & 127;
  int n = n0 + jj;
  const float4* W4 = (const float4*)(Wx + ((size_t)dir*768 + n)*256);
  const float4* A4 = (const float4*)As;
  float acc[16];
  #pragma unroll
  for (int i = 0; i < 16; ++i) acc[i] = 0.f;
  for (int k4 = 0; k4 < 64; ++k4) {
    float4 wv = W4[k4];
    #pragma unroll
    for (int i = 0; i < 16; ++i) {
      float4 av = A4[(rr*16 + i)*64 + k4];
      acc[i] += av.x*wv.x + av.y*wv.y + av.z*wv.z + av.w*wv.w;
    }
  }
  float bias = bx[dir*768 + n];
  for (int i = 0; i < 16; ++i) {
    int l = rr*16 + i;
    xp[(((size_t)dir*QL_ + l)*16 + b)*768 + n] = acc[i] + bias;
  }
}

// ---------------------------------------------------------------------------
// Persistent q-GRU v2. grid (2 dirs), block 1024 = 16 waves; wave w owns
// j-slice [16w,16w+16). B (Wh fp16) streamed from L2 (24 KB/wave/step) ->
// low VGPR, no spills. xp slab staged coalescedly into double-buffered LDS.
// h kept in 8 KB swizzled LDS (fp16, MFMA A-operand) + fp32 in regs.
// 2 barriers/step.
// ---------------------------------------------------------------------------
__global__ __launch_bounds__(1024, 4) void k_qgru(
    const int* __restrict__ questions, const _Float16* __restrict__ WhQ,
    const float* __restrict__ bh, const float* __restrict__ xp,
    float* __restrict__ qwh, float* __restrict__ qemb)
{
  const int dir = blockIdx.x;
  const int tid = threadIdx.x;
  const int lane = tid & 63, w = tid >> 6;
  const int lm = lane & 15, lq = lane >> 4;
  const int jl = w*16 + lm;

  __shared__ _Float16 hA[16*256];     // swizzled: chunk p = c ^ row
  __shared__ float xpL[2][16*768];    // [par][b][768]
  __shared__ int tokS[512];

  if (tid < 512) {
    tokS[tid] = questions[tid];
    int row = tid >> 5, c = tid & 31;
    half8 z8 = {0,0,0,0,0,0,0,0};
    *(half8*)(hA + row*256 + (c ^ row)*8) = z8;
  }

  const _Float16* pR = WhQ + ((size_t)dir*768 + jl)*256;
  const _Float16* pZ = WhQ + ((size_t)dir*768 + 256 + jl)*256;
  const _Float16* pG = WhQ + ((size_t)dir*768 + 512 + jl)*256;
  const float bh_r = bh[dir*768 + jl];
  const float bh_z = bh[dir*768 + 256 + jl];
  const float bh_n = bh[dir*768 + 512 + jl];
  float hreg[4] = {0.f,0.f,0.f,0.f};

  for (int t = 0; t < QL_; ++t) {
    int l = dir ? (QL_-1-t) : t;
    int par = t & 1;
    {
      const float4* src = (const float4*)(xp + (((size_t)dir*QL_ + l)*16)*768);
      float4* dst = (float4*)xpL[par];
      dst[tid]        = src[tid];
      dst[tid + 1024] = src[tid + 1024];
      dst[tid + 2048] = src[tid + 2048];
    }
    __syncthreads();   // xp staged; prev-step h writes visible

    floatx4 aR = {0,0,0,0}, aZ = {0,0,0,0}, aG = {0,0,0,0};
    #pragma unroll
    for (int kf = 0; kf < 8; ++kf) {
      int p = (kf*4 + lq) ^ lm;
      half8 a = *(const half8*)(hA + lm*256 + p*8);
      int k0 = kf*32 + lq*8;
      half8 br = *(const half8*)(pR + k0);
      half8 bz = *(const half8*)(pZ + k0);
      half8 bg = *(const half8*)(pG + k0);
      aR = __builtin_amdgcn_mfma_f32_16x16x32_f16(a, br, aR, 0,0,0);
      aZ = __builtin_amdgcn_mfma_f32_16x16x32_f16(a, bz, aZ, 0,0,0);
      aG = __builtin_amdgcn_mfma_f32_16x16x32_f16(a, bg, aG, 0,0,0);
    }
    __syncthreads();   // hA reads done before epilogue rewrites h

    #pragma unroll
    for (int reg = 0; reg < 4; ++reg) {
      int b = lq*4 + reg;
      const float* xb = &xpL[par][b*768];
      float r  = sigf(xb[jl]       + aR[reg] + bh_r);
      float z  = sigf(xb[256 + jl] + aZ[reg] + bh_z);
      float nt = tanhfast(xb[512 + jl] + r*(aG[reg] + bh_n));
      float hold = hreg[reg];
      float hn = (1.f - z)*nt + z*hold;
      int tk = tokS[b*QL_ + l];
      float hnew = (tk != 0) ? hn : hold;
      hreg[reg] = hnew;
      int p2 = (jl >> 3) ^ b;
      hA[b*256 + p2*8 + (jl & 7)] = (_Float16)hnew;
      qwh[((size_t)b*QL_ + l)*512 + dir*256 + jl] = (tk != 0) ? hnew : 0.f;
    }
    // no trailing barrier: next loop-top sync covers h visibility; xpL is
    // double-buffered so the next stage writes the other buffer.
  }
  #pragma unroll
  for (int reg = 0; reg < 4; ++reg) {
    int b = lq*4 + reg;
    qemb[b*512 + dir*256 + jl] = hreg[reg];
  }
}

// ---------------------------------------------------------------------------
// Persistent desc-GRU v3. grid (250,1,2), block 1024 = 16 waves, M=64 seqs.
// vs v2: tokens staged to LDS (kills 16 scalar global loads/lane/step),
// fast sig/tanh (native exp/rcp), hoisted B pointers, unroll 4.
// LDS: A2 = 64x512 fp16 XOR-swizzled (64 KB) + tokL.
// ---------------------------------------------------------------------------
__global__ __launch_bounds__(1024, 4) void k_desc_gru(
    const int* __restrict__ desc, const float* __restrict__ emb,
    const _Float16* __restrict__ Bd, const float* __restrict__ bx,
    const float* __restrict__ bh, float* __restrict__ dh)
{
  const int dir  = blockIdx.z;
  const int seq0 = blockIdx.x * 64;
  const int tid  = threadIdx.x;
  const int lane = tid & 63, w = tid >> 6;
  const int lm = lane & 15, lq = lane >> 4;
  const int j0 = w * 16;

  __shared__ _Float16 A2[64*512];   // 64 KB, swizzled (p = c ^ row over 64 chunks)
  __shared__ int tokL[2][64];

  // zero h region (chunks 32..63 per row)
  {
    int row = tid >> 4, cc = tid & 15;
    half8 z8 = {0,0,0,0,0,0,0,0};
    #pragma unroll
    for (int q = 0; q < 2; ++q) {
      int c = 32 + cc*2 + q;
      *(half8*)(A2 + row*512 + (c ^ row)*8) = z8;
    }
  }

  const int l0 = dir ? (DL_-1) : 0;
  const int dl = dir ? -1 : 1;

  auto stage_x = [&](int ll, int par) {
    int row = tid >> 4, cc = tid & 15;
    int s = seq0 + row;
    int tk = desc[(size_t)s*DL_ + ll];
    if (cc == 0) tokL[par][row] = tk;
    const float4* src = (const float4*)(emb + (size_t)tk*256);
    #pragma unroll
    for (int q = 0; q < 2; ++q) {
      int c = cc*2 + q;
      float4 v0 = src[c*2], v1 = src[c*2+1];
      half8 hv;
      hv[0]=(_Float16)v0.x; hv[1]=(_Float16)v0.y; hv[2]=(_Float16)v0.z; hv[3]=(_Float16)v0.w;
      hv[4]=(_Float16)v1.x; hv[5]=(_Float16)v1.y; hv[6]=(_Float16)v1.z; hv[7]=(_Float16)v1.w;
      *(half8*)(A2 + row*512 + (c ^ row)*8) = hv;
    }
  };
  stage_x(l0, 0);

  const _Float16* Bdir = Bd + (size_t)dir * 393216;
  const int jl = j0 + lm;
  const _Float16* pR = Bdir + (size_t)jl*512;
  const _Float16* pZ = Bdir + (size_t)(256 + jl)*512;
  const _Float16* pX = Bdir + 262144 + (size_t)jl*256;
  const _Float16* pG = Bdir + 327680 + (size_t)jl*256;

  const float bias_r = bx[dir*768 + jl]       + bh[dir*768 + jl];
  const float bias_z = bx[dir*768 + 256 + jl] + bh[dir*768 + 256 + jl];
  const float bias_n = bx[dir*768 + 512 + jl];
  const float bias_g = bh[dir*768 + 512 + jl];

  int l = l0;
  for (int t = 0; t < DL_; ++t, l += dl) {
    __syncthreads();   // staging/h-writes visible

    floatx4 accR[4], accZ[4], accN[4], accG[4];
    #pragma unroll
    for (int mi = 0; mi < 4; ++mi) {
      floatx4 z4 = {0.f,0.f,0.f,0.f};
      accR[mi]=z4; accZ[mi]=z4; accN[mi]=z4; accG[mi]=z4;
    }

    #pragma unroll
    for (int half = 0; half < 2; ++half) {
      #pragma unroll 4
      for (int kk = 0; kk < 8; ++kk) {
        int kfx = half*8 + kk;
        int k0 = kfx*32 + lq*8;
        half8 br = *(const half8*)(pR + k0);
        half8 bz = *(const half8*)(pZ + k0);
        half8 bb = half ? *(const half8*)(pG + (k0 - 256))
                        : *(const half8*)(pX + k0);
        int cb = kfx*4 + lq;
        #pragma unroll
        for (int mi = 0; mi < 4; ++mi) {
          int row = mi*16 + lm;
          half8 a = *(const half8*)(A2 + row*512 + (cb ^ row)*8);
          accR[mi] = __builtin_amdgcn_mfma_f32_16x16x32_f16(a, br, accR[mi], 0,0,0);
          accZ[mi] = __builtin_amdgcn_mfma_f32_16x16x32_f16(a, bz, accZ[mi], 0,0,0);
          if (half) accG[mi] = __builtin_amdgcn_mfma_f32_16x16x32_f16(a, bb, accG[mi], 0,0,0);
          else      accN[mi] = __builtin_amdgcn_mfma_f32_16x16x32_f16(a, bb, accN[mi], 0,0,0);
        }
      }
    }

    __syncthreads();   // all A2 reads done

    int par = t & 1;
    #pragma unroll
    for (int mi = 0; mi < 4; ++mi) {
      #pragma unroll
      for (int reg = 0; reg < 4; ++reg) {
        int m = mi*16 + lq*4 + reg;
        float r  = sigf(accR[mi][reg] + bias_r);
        float z  = sigf(accZ[mi][reg] + bias_z);
        float nt = tanhfast(accN[mi][reg] + bias_n + r*(accG[mi][reg] + bias_g));
        int c2 = 32 + (jl >> 3);
        _Float16* hp = A2 + m*512 + ((c2 ^ m)*8) + (jl & 7);
        float hold = (float)(*hp);
        float hn = (1.f - z)*nt + z*hold;
        int tk = tokL[par][m];
        float hnew = (tk != 0) ? hn : hold;
        *hp = (_Float16)hnew;
        if (t == DL_-1)
          dh[((size_t)dir*NSEQD + seq0 + m)*256 + jl] = hnew;
      }
    }
    if (t < DL_-1) stage_x(l + dl, (t+1) & 1);
  }
}

// Per t: cq = tanh(q_emb @ step_W^T + b); att softmax; ctx; u = ctx*rel_W.
__global__ __launch_bounds__(256) void k_attn(
    const float* __restrict__ qemb, const float* __restrict__ qwh,
    const float* __restrict__ sW, const float* __restrict__ sb,
    const float* __restrict__ relW, float* __restrict__ u, int t)
{
  int b = blockIdx.x, tid = threadIdx.x;
  __shared__ float qe[512];
  __shared__ float cq[512];
  __shared__ float lg[32];
  __shared__ float dist[32];
  qe[tid]     = qemb[b*512 + tid];
  qe[tid+256] = qemb[b*512 + 256 + tid];
  __syncthreads();
  const float4* qe4 = (const float4*)qe;
  for (int nn = 0; nn < 2; ++nn) {
    int n = tid + nn*256;
    const float4* w4 = (const float4*)(sW + ((size_t)t*512 + n)*512);
    float acc = 0.f;
    for (int k4 = 0; k4 < 128; ++k4) {
      float4 w = w4[k4]; float4 q = qe4[k4];
      acc += w.x*q.x + w.y*q.y + w.z*q.z + w.w*q.w;
    }
    cq[n] = tanhfast(acc + sb[t*512 + n]);
  }
  __syncthreads();
  if (tid < 32) {
    const float4* r4 = (const float4*)(qwh + ((size_t)b*QL_ + tid)*512);
    const float4* c4 = (const float4*)cq;
    float acc = 0.f;
    for (int k4 = 0; k4 < 128; ++k4) {
      float4 w = r4[k4]; float4 q = c4[k4];
      acc += w.x*q.x + w.y*q.y + w.z*q.z + w.w*q.w;
    }
    lg[tid] = acc;
  }
  __syncthreads();
  if (tid == 0) {
    float mx = lg[0];
    for (int i = 1; i < 32; ++i) mx = fmaxf(mx, lg[i]);
    float s = 0.f;
    for (int i = 0; i < 32; ++i) { float e = __expf(lg[i]-mx); dist[i] = e; s += e; }
    float inv = __builtin_amdgcn_rcpf(s);
    for (int i = 0; i < 32; ++i) dist[i] *= inv;
  }
  __syncthreads();
  for (int nn = 0; nn < 2; ++nn) {
    int c = tid + nn*256;
    float acc = 0.f;
    #pragma unroll 4
    for (int ll = 0; ll < 32; ++ll)
      acc += dist[ll] * qwh[((size_t)b*QL_ + ll)*512 + c];
    u[b*512 + c] = acc * relW[c];
  }
}

__global__ __launch_bounds__(256) void k_dlogit(
    const float* __restrict__ u, const float* __restrict__ dh,
    const float* __restrict__ relb, float* __restrict__ dprob, int t)
{
  int w = threadIdx.x >> 6, lane = threadIdx.x & 63;
  int o = blockIdx.x*4 + w;
  int b = o / 500;
  int s = t*(B_*RSZ_) + o;
  const float* e0 = dh + (size_t)s*256;
  const float* e1 = dh + (size_t)NSEQD*256 + (size_t)s*256;
  float acc = 0.f;
  #pragma unroll
  for (int i = 0; i < 4; ++i) {
    int c = lane + i*64;
    acc += u[b*512 + c]       * e0[c];
    acc += u[b*512 + 256 + c] * e1[c];
  }
  #pragma unroll
  for (int off = 32; off; off >>= 1) acc += __shfl_down(acc, off);
  if (lane == 0) dprob[o] = sigf(acc + relb[0]);
}

__global__ void k_scatter(const int* __restrict__ pair, const float* __restrict__ dprob,
                          const float* __restrict__ esrc, float* __restrict__ edst,
                          int t, int clampflag)
{
  int o = blockIdx.x*256 + threadIdx.x;
  if (o >= B_*RSZ_) return;
  int b = o / RSZ_, r = o % RSZ_;
  const int* pp = pair + (((size_t)t*B_ + b)*RSZ_ + r)*2;
  int sub = pp[0], obj = pp[1];
  float v = esrc[(size_t)b*NE_ + sub];
  if (clampflag) v = fminf(v, 1.0f);
  atomicAdd(edst + (size_t)b*NE_ + obj, v * dprob[o]);
}

__global__ __launch_bounds__(256) void k_final(
    const float* __restrict__ qemb, const float* __restrict__ W,
    const float* __restrict__ bias, const float* __restrict__ efin,
    float* __restrict__ out)
{
  int tid = threadIdx.x;
  int lane = tid & 63;
  int ks = lane & 15, bg = lane >> 4;
  int b = (tid >> 6)*4 + bg;
  float q[32];
  {
    const float4* q4 = (const float4*)(qemb + b*512 + ks*32);
    #pragma unroll
    for (int i = 0; i < 8; ++i) {
      float4 v = q4[i];
      q[4*i]=v.x; q[4*i+1]=v.y; q[4*i+2]=v.z; q[4*i+3]=v.w;
    }
  }
  int e0 = blockIdx.x*256;
  int eend = (e0+256 < NE_) ? e0+256 : NE_;
  for (int e = e0; e < eend; ++e) {
    const float4* w4 = (const float4*)(W + (size_t)e*512 + ks*32);
    float acc = 0.f;
    #pragma unroll
    for (int i = 0; i < 8; ++i) {
      float4 v = w4[i];
      acc += v.x*q[4*i] + v.y*q[4*i+1] + v.z*q[4*i+2] + v.w*q[4*i+3];
    }
    acc += __shfl_xor(acc, 1);
    acc += __shfl_xor(acc, 2);
    acc += __shfl_xor(acc, 4);
    acc += __shfl_xor(acc, 8);
    if (ks == 0) {
      float msk = sigf(acc + bias[e]);
      float ev = fminf(efin[(size_t)b*NE_ + e], 1.0f);
      out[(size_t)b*NE_ + e] = ev * msk;
    }
  }
}

extern "C" void kernel_launch(void* const* d_in, const int* in_sizes, int n_in,
                              void* d_out, int out_size, void* d_ws, size_t ws_size,
                              hipStream_t stream)
{
  const int*   questions = (const int*)d_in[0];
  const float* e_s   = (const float*)d_in[1];
  const int*   pair  = (const int*)d_in[2];
  const int*   desc  = (const int*)d_in[3];
  const float* emb   = (const float*)d_in[4];
  const float* qWx   = (const float*)d_in[5];
  const float* qWh   = (const float*)d_in[6];
  const float* qbx   = (const float*)d_in[7];
  const float* qbh   = (const float*)d_in[8];
  const float* dWx   = (const float*)d_in[9];
  const float* dWh   = (const float*)d_in[10];
  const float* dbx   = (const float*)d_in[11];
  const float* dbh   = (const float*)d_in[12];
  const float* stepW = (const float*)d_in[13];
  const float* stepb = (const float*)d_in[14];
  const float* relW  = (const float*)d_in[15];
  const float* relb  = (const float*)d_in[16];
  const float* qclsW = (const float*)d_in[17];
  const float* qclsb = (const float*)d_in[18];
  float* out = (float*)d_out;

  char* ws = (char*)d_ws;
  size_t off = 0;
  auto alloc = [&](size_t bytes)->void* {
    void* p = ws + off; off += (bytes + 255) & ~(size_t)255; return p;
  };
  _Float16* Bd   = (_Float16*)alloc((size_t)2*393216*sizeof(_Float16)); // 1.5 MB
  _Float16* WhQ  = (_Float16*)alloc((size_t)2*768*256*sizeof(_Float16));// 0.75 MB
  float* xp   = (float*)alloc((size_t)2*QL_*16*768*sizeof(float));      // 3.1 MB
  float* qemb = (float*)alloc((size_t)16*512*sizeof(float));
  float* qwh  = (float*)alloc((size_t)16*QL_*512*sizeof(float));        // 1 MB
  float* dh   = (float*)alloc((size_t)2*NSEQD*256*sizeof(float));       // 32.8 MB
  float* u    = (float*)alloc((size_t)16*512*sizeof(float));
  float* dprob= (float*)alloc((size_t)B_*RSZ_*sizeof(float));
  float* ebuf = (float*)alloc((size_t)2*B_*NE_*sizeof(float));          // 12.8 MB

  hipMemsetAsync(ebuf, 0, (size_t)2*B_*NE_*sizeof(float), stream);

  k_prep_desc<<<3072, 256, 0, stream>>>(dWx, dWh, Bd);
  k_prep_qwh<<<1536, 256, 0, stream>>>(qWh, WhQ);

  k_xproj<<<dim3(16,6,2), 256, 0, stream>>>(questions, emb, qWx, qbx, xp);
  k_qgru<<<2, 1024, 0, stream>>>(questions, WhQ, qbh, xp, qwh, qemb);

  k_desc_gru<<<dim3(250,1,2), 1024, 0, stream>>>(desc, emb, Bd, dbx, dbh, dh);

  for (int t = 0; t < T_; ++t) {
    k_attn<<<16, 256, 0, stream>>>(qemb, qwh, stepW, stepb, relW, u, t);
    k_dlogit<<<2000, 256, 0, stream>>>(u, dh, relb, dprob, t);
    const float* esrc = (t == 0) ? e_s : ebuf;
    float* edst = ebuf + (size_t)t*B_*NE_;
    k_scatter<<<32, 256, 0, stream>>>(pair, dprob, esrc, edst, t, t);
  }
  k_final<<<(NE_+255)/256, 256, 0, stream>>>(qemb, qclsW, qclsb, ebuf + (size_t)B_*NE_, out);
}